// Round 1
// baseline (107.504 us; speedup 1.0000x reference)
//
#include <hip/hip_runtime.h>
#include <hip/hip_bf16.h>
#include <cstdint>

// HopfieldLayer: out = attn(attn(R,Y,Y), Y, Y), H=8 heads, E=64, softmax scale 1/8.
// Plan: fp32->bf16 convert (Q pre-scaled by (1/8)*log2(e)), then 2x flash-attn
// with bf16 MFMA 16x16x32, swapped QK^T (mfma(K,Q)), single sub-tiled LDS tile
// serving K row-reads and V^T hardware-transpose reads (ds_read_b64_tr_b16).

typedef __attribute__((ext_vector_type(8))) short bf16x8;
typedef __attribute__((ext_vector_type(4))) short short4v;
typedef __attribute__((ext_vector_type(4))) float f32x4;

constexpr int B_ = 2, L_ = 2048, S_ = 2048, H_ = 8, E_ = 64, DM_ = 512;
constexpr float SCALE2 = 0.18033688011112042f; // (1/sqrt(64)) * log2(e)

__device__ __forceinline__ ushort f2bf(float a) {
  uint32_t u = __builtin_bit_cast(uint32_t, a);
  return (ushort)((u + 0x7fffu + ((u >> 16) & 1u)) >> 16); // RNE, finite inputs
}
__device__ __forceinline__ uint32_t bf16pack(float a, float b) {
  uint32_t ua = __builtin_bit_cast(uint32_t, a);
  uint32_t ub = __builtin_bit_cast(uint32_t, b);
  ua = (ua + 0x7fffu + ((ua >> 16) & 1u)) >> 16;
  ub = (ub + 0x7fffu + ((ub >> 16) & 1u)) >> 16;
  return (ua & 0xffffu) | (ub << 16);
}

__global__ void cvt_kernel(const float* __restrict__ in, ushort* __restrict__ out,
                           int n4, float mul) {
  int i = blockIdx.x * 256 + threadIdx.x;
  if (i >= n4) return;
  float4 v = reinterpret_cast<const float4*>(in)[i];
  ushort4 o;
  o.x = f2bf(v.x * mul); o.y = f2bf(v.y * mul);
  o.z = f2bf(v.z * mul); o.w = f2bf(v.w * mul);
  reinterpret_cast<ushort4*>(out)[i] = o;
}

// LDS tile layout: 64s x 64e bf16, sub-tiled for tr-reads:
//   idx(s,e) = block * 64 + (s&3)*16 + (e&15),
//   block(par=(s>>2)&1, eb=e>>4, sbh=s>>3) = (par*4 + eb)*8 + sbh
// - staging: thread's 8 contiguous-e values land contiguous -> one ds_write_b128
// - K A-frag (row s, 8 contiguous e): one ds_read_b128
// - V^T A-frag (col e, 8 contiguous s): two ds_read_b64_tr_b16
template <bool OUT_F32>
__global__ __launch_bounds__(256, 2) void attn_kernel(
    const ushort* __restrict__ Qb,  // bf16 [B,L,512], pre-scaled by SCALE2
    const ushort* __restrict__ Yb,  // bf16 [B,S,512]
    float* __restrict__ outF, ushort* __restrict__ outB) {
  __shared__ ushort Vsub[4096]; // 8 KB

  const int tid = threadIdx.x;
  const int lane = tid & 63;
  const int wid = tid >> 6;
  const int g = lane >> 4;   // 16-lane group 0..3
  const int qi = lane & 15;  // this lane's q column

  const int wg = blockIdx.x;
  const int qt = wg & 31;         // L/64 = 32 q-tiles
  const int h = (wg >> 5) & 7;
  const int b = wg >> 8;

  const int qglob = qt * 64 + wid * 16 + qi;
  const size_t qrow_off = (size_t)(b * L_ + qglob) * DM_ + h * E_;

  // Q B-fragments (B[k=e][n=q]: lane holds Q[qi][8 contiguous e]) — row reads
  bf16x8 qf0 = *reinterpret_cast<const bf16x8*>(Qb + qrow_off + g * 8);
  bf16x8 qf1 = *reinterpret_cast<const bf16x8*>(Qb + qrow_off + 32 + g * 8);

  f32x4 oacc[4];
#pragma unroll
  for (int et = 0; et < 4; ++et) oacc[et] = f32x4{0.f, 0.f, 0.f, 0.f};
  float m = -1e30f, lsum = 0.f;

  const size_t ybase = (size_t)(b * S_) * DM_ + h * E_;
  const uint32_t vb = (uint32_t)(uintptr_t)(&Vsub[0]); // LDS byte offset

  for (int s0 = 0; s0 < S_; s0 += 64) {
    __syncthreads();
    // ---- stage KV tile (K == V): 2 x (16B global read + 16B LDS write)/thread
#pragma unroll
    for (int it = 0; it < 2; ++it) {
      int cidx = tid + it * 256;
      int r = cidx >> 3, c = cidx & 7; // s-row, e-chunk
      uint4 d = *reinterpret_cast<const uint4*>(Yb + ybase + (size_t)(s0 + r) * DM_ + c * 8);
      int idx = ((((r >> 2) & 1) * 4 + (c >> 1)) * 8 + (r >> 3)) * 64 + (r & 3) * 16 + (c & 1) * 8;
      *reinterpret_cast<uint4*>(&Vsub[idx]) = d;
    }
    __syncthreads();

    // ---- S^T = mfma(A=K, B=Q): D[s-in-16][q], row=4g+reg, col=qi
    f32x4 st[4];
#pragma unroll
    for (int nt = 0; nt < 4; ++nt) {
      f32x4 acc = f32x4{0.f, 0.f, 0.f, 0.f};
#pragma unroll
      for (int eck = 0; eck < 2; ++eck) {
        int s = nt * 16 + qi;
        int idx = ((((s >> 2) & 1) * 4 + (eck * 2 + (g >> 1))) * 8 + (s >> 3)) * 64 +
                  (s & 3) * 16 + (g & 1) * 8;
        bf16x8 ak = *reinterpret_cast<const bf16x8*>(&Vsub[idx]);
        acc = __builtin_amdgcn_mfma_f32_16x16x32_bf16(ak, eck ? qf1 : qf0, acc, 0, 0, 0);
      }
      st[nt] = acc;
    }

    // ---- online softmax (z already in exp2 domain: Q pre-scaled)
    float z[16];
    float tm = -1e30f;
#pragma unroll
    for (int nt = 0; nt < 4; ++nt)
#pragma unroll
      for (int r = 0; r < 4; ++r) {
        float v = st[nt][r];
        z[nt * 4 + r] = v;
        tm = fmaxf(tm, v);
      }
    tm = fmaxf(tm, __shfl_xor(tm, 16));
    tm = fmaxf(tm, __shfl_xor(tm, 32));
    float mnew = fmaxf(m, tm);
    float alpha = __builtin_amdgcn_exp2f(m - mnew);
    m = mnew;
    lsum *= alpha;
#pragma unroll
    for (int et = 0; et < 4; ++et) oacc[et] *= alpha;
    float p[16];
#pragma unroll
    for (int i = 0; i < 16; ++i) {
      p[i] = __builtin_amdgcn_exp2f(z[i] - m);
      lsum += p[i];
    }

    // ---- PV: O^T[e][q] += mfma(A=V^T, B=P^T) over 2 k-chunks of 32 s
#pragma unroll
    for (int ck = 0; ck < 2; ++ck) {
      // P^T redistribution: lane(g,qi) holds P[s=nt*16+4g+r][qi]; B-frag needs
      // s_local = 8g+j. Sources: lanes qi+16*{g'lo,g'hi}, u = g>>1 selects nt.
      uint32_t W00 = bf16pack(p[(2 * ck) * 4 + 0], p[(2 * ck) * 4 + 1]);
      uint32_t W01 = bf16pack(p[(2 * ck) * 4 + 2], p[(2 * ck) * 4 + 3]);
      uint32_t W10 = bf16pack(p[(2 * ck + 1) * 4 + 0], p[(2 * ck + 1) * 4 + 1]);
      uint32_t W11 = bf16pack(p[(2 * ck + 1) * 4 + 2], p[(2 * ck + 1) * 4 + 3]);
      int sl_lo = qi + 32 * (g & 1);
      int sl_hi = sl_lo + 16;
      uint32_t A0 = (uint32_t)__shfl((int)W00, sl_lo), A1 = (uint32_t)__shfl((int)W01, sl_lo);
      uint32_t A2 = (uint32_t)__shfl((int)W10, sl_lo), A3 = (uint32_t)__shfl((int)W11, sl_lo);
      uint32_t Bb0 = (uint32_t)__shfl((int)W00, sl_hi), Bb1 = (uint32_t)__shfl((int)W01, sl_hi);
      uint32_t Bb2 = (uint32_t)__shfl((int)W10, sl_hi), Bb3 = (uint32_t)__shfl((int)W11, sl_hi);
      bool uhi = (g >> 1) != 0;
      uint4 pw;
      pw.x = uhi ? A2 : A0;
      pw.y = uhi ? A3 : A1;
      pw.z = uhi ? Bb2 : Bb0;
      pw.w = uhi ? Bb3 : Bb1;
      bf16x8 pfrag = __builtin_bit_cast(bf16x8, pw);

      // V^T A-frags via hardware transpose reads (lane gets col e=et*16+qi,
      // k=j over 4 s-rows; group g covers s = 32ck+8g+4p+j)
      short4v t[4][2];
#pragma unroll
      for (int et = 0; et < 4; ++et)
#pragma unroll
        for (int pb = 0; pb < 2; ++pb) {
          uint32_t addr = vb + (uint32_t)((((pb * 4 + et) * 8) + 4 * ck) * 128) + 8u * (uint32_t)lane;
          asm volatile("ds_read_b64_tr_b16 %0, %1" : "=v"(t[et][pb]) : "v"(addr));
        }
      asm volatile("s_waitcnt lgkmcnt(0)" ::: "memory");
      __builtin_amdgcn_sched_barrier(0); // rule #18: keep MFMA below the wait

#pragma unroll
      for (int et = 0; et < 4; ++et) {
        short4v lo = t[et][0], hi = t[et][1];
        bf16x8 vf;
        vf[0] = lo[0]; vf[1] = lo[1]; vf[2] = lo[2]; vf[3] = lo[3];
        vf[4] = hi[0]; vf[5] = hi[1]; vf[6] = hi[2]; vf[7] = hi[3];
        oacc[et] = __builtin_amdgcn_mfma_f32_16x16x32_bf16(vf, pfrag, oacc[et], 0, 0, 0);
      }
    }
  }

  // ---- epilogue: normalize; lane holds O^T[e=et*16+4g+r][q=qi]
  lsum += __shfl_xor(lsum, 16);
  lsum += __shfl_xor(lsum, 32);
  float inv = 1.0f / lsum;
#pragma unroll
  for (int et = 0; et < 4; ++et)
#pragma unroll
    for (int r = 0; r < 4; ++r) {
      int e = et * 16 + 4 * g + r;
      float val = oacc[et][r] * inv;
      if constexpr (OUT_F32) outF[qrow_off + e] = val;
      else outB[qrow_off + e] = f2bf(val * SCALE2); // pre-scale for step-2 Q
    }
}

extern "C" void kernel_launch(void* const* d_in, const int* in_sizes, int n_in,
                              void* d_out, int out_size, void* d_ws, size_t ws_size,
                              hipStream_t stream) {
  const float* R = (const float*)d_in[0];
  const float* Y = (const float*)d_in[1];
  float* outF = (float*)d_out;

  constexpr int NE = B_ * L_ * DM_; // 2,097,152 elements per tensor
  ushort* Rb = (ushort*)d_ws;
  ushort* Yb = Rb + NE;
  ushort* q1 = Yb + NE;

  const int n4 = NE / 4;
  cvt_kernel<<<dim3((n4 + 255) / 256), 256, 0, stream>>>(R, Rb, n4, SCALE2);
  cvt_kernel<<<dim3((n4 + 255) / 256), 256, 0, stream>>>(Y, Yb, n4, 1.0f);

  const int ngrid = B_ * H_ * (L_ / 64); // 512 workgroups
  attn_kernel<false><<<dim3(ngrid), 256, 0, stream>>>(Rb, Yb, nullptr, q1);
  attn_kernel<true><<<dim3(ngrid), 256, 0, stream>>>(q1, Yb, outF, nullptr);
}

// Round 2
// 96.571 us; speedup vs baseline: 1.1132x; 1.1132x over previous
//
#include <hip/hip_runtime.h>
#include <hip/hip_bf16.h>
#include <cstdint>

// HopfieldLayer: out = attn(attn(R,Y,Y), Y, Y), H=8 heads, E=64, scale 1/8.
// R2: double-buffered KV tile + async staging (global->reg early, vmcnt+ds_write
// late, ONE barrier/tile) and P^T redistribution through wave-local LDS
// (4x ds_write_b64 + 2x ds_read_b128) replacing 16 ds_bpermute + selects.

typedef __attribute__((ext_vector_type(8))) short bf16x8;
typedef __attribute__((ext_vector_type(4))) short short4v;
typedef __attribute__((ext_vector_type(4))) float f32x4;

constexpr int B_ = 2, L_ = 2048, S_ = 2048, H_ = 8, E_ = 64, DM_ = 512;
constexpr int NT_ = S_ / 64; // 32 KV tiles
constexpr float SCALE2 = 0.18033688011112042f; // (1/sqrt(64)) * log2(e)

__device__ __forceinline__ ushort f2bf(float a) {
  uint32_t u = __builtin_bit_cast(uint32_t, a);
  return (ushort)((u + 0x7fffu + ((u >> 16) & 1u)) >> 16); // RNE, finite inputs
}
__device__ __forceinline__ uint32_t bf16pack(float a, float b) {
  uint32_t ua = __builtin_bit_cast(uint32_t, a);
  uint32_t ub = __builtin_bit_cast(uint32_t, b);
  ua = (ua + 0x7fffu + ((ua >> 16) & 1u)) >> 16;
  ub = (ub + 0x7fffu + ((ub >> 16) & 1u)) >> 16;
  return (ua & 0xffffu) | (ub << 16);
}

__global__ void cvt_kernel(const float* __restrict__ in, ushort* __restrict__ out,
                           int n4, float mul) {
  int i = blockIdx.x * 256 + threadIdx.x;
  if (i >= n4) return;
  float4 v = reinterpret_cast<const float4*>(in)[i];
  ushort4 o;
  o.x = f2bf(v.x * mul); o.y = f2bf(v.y * mul);
  o.z = f2bf(v.z * mul); o.w = f2bf(v.w * mul);
  reinterpret_cast<ushort4*>(out)[i] = o;
}

// KV LDS tile: 64s x 64e bf16, sub-tiled for tr-reads:
//   idx(s,e) = block*64 + (s&3)*16 + (e&15),
//   block = (((s>>2)&1)*4 + (e>>4))*8 + (s>>3)
// P LDS (per wave, 512 u32): [nt][qi][g'][w]: u32 idx = ((nt*16+qi)*4+g')*2+w
template <bool OUT_F32>
__global__ __launch_bounds__(256, 2) void attn_kernel(
    const ushort* __restrict__ Qb,  // bf16 [B,L,512], pre-scaled by SCALE2
    const ushort* __restrict__ Yb,  // bf16 [B,S,512]
    float* __restrict__ outF, ushort* __restrict__ outB) {
  __shared__ ushort Vsub[2][4096]; // 2 x 8 KB KV tiles
  __shared__ uint32_t Plds[4][512]; // 8 KB, wave-private P^T staging

  const int tid = threadIdx.x;
  const int lane = tid & 63;
  const int wid = tid >> 6;
  const int g = lane >> 4;   // 16-lane group 0..3
  const int qi = lane & 15;  // this lane's q column

  const int wg = blockIdx.x;
  const int qt = wg & 31;         // L/64 = 32 q-tiles
  const int h = (wg >> 5) & 7;
  const int b = wg >> 8;

  const int qglob = qt * 64 + wid * 16 + qi;
  const size_t qrow_off = (size_t)(b * L_ + qglob) * DM_ + h * E_;

  // Q B-fragments (B[k=e][n=q]: lane holds Q[qi][8 contiguous e]) — row reads
  bf16x8 qf0 = *reinterpret_cast<const bf16x8*>(Qb + qrow_off + g * 8);
  bf16x8 qf1 = *reinterpret_cast<const bf16x8*>(Qb + qrow_off + 32 + g * 8);

  f32x4 oacc[4];
#pragma unroll
  for (int et = 0; et < 4; ++et) oacc[et] = f32x4{0.f, 0.f, 0.f, 0.f};
  float m = -1e30f, lsum = 0.f;

  const size_t ybase = (size_t)(b * S_) * DM_ + h * E_;

  // staging geometry for this thread's 2 chunks (cidx = tid + it*256)
  const int r0c = tid >> 3, c0c = tid & 7;
  const int r1c = (tid + 256) >> 3, c1c = tid & 7; // (tid+256)&7 == tid&7
  const int lidx0 = ((((r0c >> 2) & 1) * 4 + (c0c >> 1)) * 8 + (r0c >> 3)) * 64 +
                    (r0c & 3) * 16 + (c0c & 1) * 8;
  const int lidx1 = ((((r1c >> 2) & 1) * 4 + (c1c >> 1)) * 8 + (r1c >> 3)) * 64 +
                    (r1c & 3) * 16 + (c1c & 1) * 8;
  const ushort* gsrc0 = Yb + ybase + (size_t)r0c * DM_ + c0c * 8;
  const ushort* gsrc1 = Yb + ybase + (size_t)r1c * DM_ + c1c * 8;

  // ---- prologue: stage tile 0 into buffer 0
  {
    uint4 d0 = *reinterpret_cast<const uint4*>(gsrc0);
    uint4 d1 = *reinterpret_cast<const uint4*>(gsrc1);
    *reinterpret_cast<uint4*>(&Vsub[0][lidx0]) = d0;
    *reinterpret_cast<uint4*>(&Vsub[0][lidx1]) = d1;
  }
  __syncthreads();

  const uint32_t vb0 = (uint32_t)(uintptr_t)(&Vsub[0][0]);
  int cur = 0;

  for (int t = 0; t < NT_; ++t) {
    // ---- issue next tile's global loads early (latency hides under compute)
    const int tn = (t + 1 < NT_) ? t + 1 : t;
    uint4 pf0 = *reinterpret_cast<const uint4*>(gsrc0 + (size_t)tn * 64 * DM_);
    uint4 pf1 = *reinterpret_cast<const uint4*>(gsrc1 + (size_t)tn * 64 * DM_);

    const ushort* Vc = &Vsub[cur][0];
    const uint32_t vbc = vb0 + (uint32_t)(cur * 8192);

    // ---- S^T = mfma(A=K, B=Q): D[s-in-16][q], row=4g+reg, col=qi
    f32x4 st[4];
#pragma unroll
    for (int nt = 0; nt < 4; ++nt) {
      f32x4 acc = f32x4{0.f, 0.f, 0.f, 0.f};
#pragma unroll
      for (int eck = 0; eck < 2; ++eck) {
        int s = nt * 16 + qi;
        int idx = ((((s >> 2) & 1) * 4 + (eck * 2 + (g >> 1))) * 8 + (s >> 3)) * 64 +
                  (s & 3) * 16 + (g & 1) * 8;
        bf16x8 ak = *reinterpret_cast<const bf16x8*>(&Vc[idx]);
        acc = __builtin_amdgcn_mfma_f32_16x16x32_bf16(ak, eck ? qf1 : qf0, acc, 0, 0, 0);
      }
      st[nt] = acc;
    }

    // ---- online softmax (z already in exp2 domain: Q pre-scaled)
    float z[16];
    float tm = -1e30f;
#pragma unroll
    for (int nt = 0; nt < 4; ++nt)
#pragma unroll
      for (int r = 0; r < 4; ++r) {
        float v = st[nt][r];
        z[nt * 4 + r] = v;
        tm = fmaxf(tm, v);
      }
    tm = fmaxf(tm, __shfl_xor(tm, 16));
    tm = fmaxf(tm, __shfl_xor(tm, 32));
    float mnew = fmaxf(m, tm);
    float alpha = __builtin_amdgcn_exp2f(m - mnew);
    m = mnew;
    lsum *= alpha;
#pragma unroll
    for (int et = 0; et < 4; ++et) oacc[et] *= alpha;
    float p[16];
#pragma unroll
    for (int i = 0; i < 16; ++i) {
      p[i] = __builtin_amdgcn_exp2f(z[i] - m);
      lsum += p[i];
    }

    // ---- P^T to wave-local LDS: [nt][qi][g][w]
#pragma unroll
    for (int nt = 0; nt < 4; ++nt) {
      uint2 w;
      w.x = bf16pack(p[nt * 4 + 0], p[nt * 4 + 1]);
      w.y = bf16pack(p[nt * 4 + 2], p[nt * 4 + 3]);
      *reinterpret_cast<uint2*>(&Plds[wid][((nt * 16 + qi) * 4 + g) * 2]) = w;
    }

    // ---- PV: O^T[e][q] += mfma(A=V^T, B=P^T) over 2 k-chunks of 32 s
#pragma unroll
    for (int ck = 0; ck < 2; ++ck) {
      // B-frag: 4 contiguous u32 = (nt=2ck+(g>>1), qi, g'=2(g&1), w=0,1),(g'+1, w=0,1)
      uint4 pw = *reinterpret_cast<const uint4*>(
          &Plds[wid][(((2 * ck + (g >> 1)) * 16 + qi) * 4 + 2 * (g & 1)) * 2]);
      bf16x8 pfrag = __builtin_bit_cast(bf16x8, pw);

      // V^T A-frags via hardware transpose reads (lane gets col e=et*16+qi,
      // k=j over 4 s-rows; group g covers s = 32ck+8g+4pb+j)
      short4v tr[4][2];
#pragma unroll
      for (int et = 0; et < 4; ++et)
#pragma unroll
        for (int pb = 0; pb < 2; ++pb) {
          uint32_t addr = vbc + (uint32_t)((((pb * 4 + et) * 8) + 4 * ck) * 128) + 8u * (uint32_t)lane;
          asm volatile("ds_read_b64_tr_b16 %0, %1" : "=v"(tr[et][pb]) : "v"(addr));
        }
      asm volatile("s_waitcnt lgkmcnt(0)" ::: "memory");
      __builtin_amdgcn_sched_barrier(0); // rule #18: keep MFMA below the wait

#pragma unroll
      for (int et = 0; et < 4; ++et) {
        short4v lo = tr[et][0], hi = tr[et][1];
        bf16x8 vf;
        vf[0] = lo[0]; vf[1] = lo[1]; vf[2] = lo[2]; vf[3] = lo[3];
        vf[4] = hi[0]; vf[5] = hi[1]; vf[6] = hi[2]; vf[7] = hi[3];
        oacc[et] = __builtin_amdgcn_mfma_f32_16x16x32_bf16(vf, pfrag, oacc[et], 0, 0, 0);
      }
    }

    // ---- write next tile into the other buffer; single barrier per tile
    if (t + 1 < NT_) {
      *reinterpret_cast<uint4*>(&Vsub[cur ^ 1][lidx0]) = pf0; // waits vmcnt here
      *reinterpret_cast<uint4*>(&Vsub[cur ^ 1][lidx1]) = pf1;
      __syncthreads();
      cur ^= 1;
    }
  }

  // ---- epilogue: normalize; lane holds O^T[e=et*16+4g+r][q=qi]
  lsum += __shfl_xor(lsum, 16);
  lsum += __shfl_xor(lsum, 32);
  float inv = 1.0f / lsum;
#pragma unroll
  for (int et = 0; et < 4; ++et)
#pragma unroll
    for (int r = 0; r < 4; ++r) {
      int e = et * 16 + 4 * g + r;
      float val = oacc[et][r] * inv;
      if constexpr (OUT_F32) outF[qrow_off + e] = val;
      else outB[qrow_off + e] = f2bf(val * SCALE2); // pre-scale for step-2 Q
    }
}

extern "C" void kernel_launch(void* const* d_in, const int* in_sizes, int n_in,
                              void* d_out, int out_size, void* d_ws, size_t ws_size,
                              hipStream_t stream) {
  const float* R = (const float*)d_in[0];
  const float* Y = (const float*)d_in[1];
  float* outF = (float*)d_out;

  constexpr int NE = B_ * L_ * DM_; // 2,097,152 elements per tensor
  ushort* Rb = (ushort*)d_ws;
  ushort* Yb = Rb + NE;
  ushort* q1 = Yb + NE;

  const int n4 = NE / 4;
  cvt_kernel<<<dim3((n4 + 255) / 256), 256, 0, stream>>>(R, Rb, n4, SCALE2);
  cvt_kernel<<<dim3((n4 + 255) / 256), 256, 0, stream>>>(Y, Yb, n4, 1.0f);

  const int ngrid = B_ * H_ * (L_ / 64); // 512 workgroups
  attn_kernel<false><<<dim3(ngrid), 256, 0, stream>>>(Rb, Yb, nullptr, q1);
  attn_kernel<true><<<dim3(ngrid), 256, 0, stream>>>(q1, Yb, outF, nullptr);
}